// Round 3
// baseline (849.834 us; speedup 1.0000x reference)
//
#include <hip/hip_runtime.h>
#include <hip/hip_bf16.h>
#include <math.h>

// Problem dims
constexpr int NB    = 64;
constexpr int NTX   = 1024;
constexpr int NAD   = 1024;   // ADIM
constexpr int NU    = 1024;   // UNITS
constexpr int NE    = 512;    // EDIM
constexpr int NV    = 32000;  // VOCAB
constexpr int KX    = NAD + NE;      // 1536 (rows of Wx)
constexpr int KTOT  = KX + NU;       // 2560 (concat K for z-GEMM)
constexpr int G4    = 4 * NU;        // 4096
constexpr int NTC   = 16;            // t-chunks for context reduce

// Workspace layout (floats)
constexpr size_t OFF_AT  = 0;                          // At[k][b]  : KTOT*NB   = 163840
constexpr size_t OFF_Z   = OFF_AT + (size_t)KTOT * NB; // zacc[b][u]: NB*G4     = 262144
constexpr size_t OFF_HT  = OFF_Z + (size_t)NB * G4;    // Ht[k][b]  : NU*NB     = 65536
constexpr size_t OFF_SCR = OFF_HT + (size_t)NU * NB;   // union{ part[16][B][AD]=1048576 , logits[B][V]=2048000 }

// Out layout (fp32 elements), reference return order:
// (y_pred[B,V], context[B,1,A], alpha[B,Tx], h_new[B,U], c_new[B,U])
constexpr size_t OUT_Y     = 0;
constexpr size_t OUT_CTX   = (size_t)NB * NV;           // 2048000
constexpr size_t OUT_ALPHA = OUT_CTX + (size_t)NB * NAD;
constexpr size_t OUT_H     = OUT_ALPHA + (size_t)NB * NTX;
constexpr size_t OUT_C     = OUT_H + (size_t)NB * NU;

__device__ __forceinline__ float sigf(float x) { return 1.0f / (1.0f + __expf(-x)); }

// ---- 1) z := bl (bias init; also serves as the atomic accumulator init) ----
__global__ __launch_bounds__(256) void k_zinit(const float* __restrict__ bl,
                                               float* __restrict__ zacc) {
    int i = blockIdx.x * 256 + threadIdx.x;      // grid 1024*256 == NB*G4 exactly
    zacc[i] = bl[i & (G4 - 1)];
}

// ---- 2) context partials: part[tc][b][d] = sum_{t in chunk} a[b][t][d] ------
__global__ __launch_bounds__(256) void k_ctx(const float* __restrict__ a,
                                             float* __restrict__ part) {
    int tc = blockIdx.x, b = blockIdx.y, tid = threadIdx.x;
    float4 acc = make_float4(0.f, 0.f, 0.f, 0.f);
    int t0 = tc * (NTX / NTC);
    #pragma unroll 4
    for (int tt = 0; tt < NTX / NTC; ++tt) {
        const float4* row = (const float4*)(a + ((size_t)b * NTX + t0 + tt) * NAD);
        float4 v = row[tid];                     // 4 f32, coalesced 16B/lane
        acc.x += v.x; acc.y += v.y; acc.z += v.z; acc.w += v.w;
    }
    float4* p4 = (float4*)(part + ((size_t)tc * NB + b) * NAD + tid * 4);
    *p4 = acc;
}

// ---- 3) finalize context; build At[k][b] = [ctx | emb | h]; alpha := 1 ------
__global__ __launch_bounds__(128) void k_ctx_fin(const float* __restrict__ part,
                                                 const int* __restrict__ X,
                                                 const float* __restrict__ emb,
                                                 const float* __restrict__ h,
                                                 float* __restrict__ At,
                                                 float* __restrict__ out_ctx,
                                                 float* __restrict__ out_alpha) {
    int b = blockIdx.x, tid = threadIdx.x;
    int d0 = tid * 8;
    float s[8] = {};
    for (int tc = 0; tc < NTC; ++tc) {
        const float* p = part + ((size_t)tc * NB + b) * NAD + d0;
        #pragma unroll
        for (int i = 0; i < 8; ++i) s[i] += p[i];
    }
    #pragma unroll
    for (int i = 0; i < 8; ++i) {
        At[(size_t)(d0 + i) * NB + b] = s[i];
        out_ctx[(size_t)b * NAD + d0 + i] = s[i];
    }
    int row = X[b];
    for (int j = tid; j < NE; j += 128)
        At[(size_t)(NAD + j) * NB + b] = emb[(size_t)row * NE + j];
    for (int j = tid; j < NU; j += 128)
        At[(size_t)(KX + j) * NB + b] = h[(size_t)b * NU + j];
    for (int j = tid; j < NTX; j += 128)
        out_alpha[(size_t)b * NTX + j] = 1.0f;
}

// ---- 4) z-GEMM: zacc[b][u] += sum_k At[k][b] * W[k][u], K split 8-way -------
__global__ __launch_bounds__(256) void k_zgemm(const float* __restrict__ At,
                                               const float* __restrict__ Wx,
                                               const float* __restrict__ Wh,
                                               float* __restrict__ zacc) {
    int tid = threadIdx.x;
    int u = blockIdx.x * 64 + (tid & 63);
    int b0 = __builtin_amdgcn_readfirstlane(tid >> 6) * 16;  // wave-uniform
    int k0 = blockIdx.y * (KTOT / 8);                        // 320
    float acc[16] = {};
    for (int kk = 0; kk < KTOT / 8; ++kk) {
        int k = k0 + kk;
        float w = (k < KX) ? Wx[(size_t)k * G4 + u]
                           : Wh[(size_t)(k - KX) * G4 + u];
        const float* ap = At + (size_t)k * NB + b0;          // wave-uniform base
        #pragma unroll
        for (int i = 0; i < 16; ++i) acc[i] = fmaf(ap[i], w, acc[i]);
    }
    #pragma unroll
    for (int i = 0; i < 16; ++i)
        atomicAdd(&zacc[(size_t)(b0 + i) * G4 + u], acc[i]);
}

// ---- 5) gates: c_new, h_new; Ht[k][b] for the vocab GEMM --------------------
__global__ __launch_bounds__(256) void k_gates(const float* __restrict__ zacc,
                                               const float* __restrict__ c,
                                               float* __restrict__ out_h,
                                               float* __restrict__ out_c,
                                               float* __restrict__ Ht) {
    int b = blockIdx.x, tid = threadIdx.x;
    const float* z = zacc + (size_t)b * G4;
    #pragma unroll
    for (int l = 0; l < 4; ++l) {
        int j = tid * 4 + l;
        float zi = z[j], zf = z[NU + j], zg = z[2 * NU + j], zo = z[3 * NU + j];
        float cf = c[(size_t)b * NU + j];
        float cn = sigf(zf) * cf + sigf(zi) * tanhf(zg);
        float hn = sigf(zo) * tanhf(cn);
        out_c[(size_t)b * NU + j] = cn;
        out_h[(size_t)b * NU + j] = hn;
        Ht[(size_t)j * NB + b] = hn;
    }
}

// ---- 6) vocab GEMM: logits[b][u] = sum_k Ht[k][b]*Wv[k][u] + bv[u] ----------
__global__ __launch_bounds__(256) void k_vgemm(const float* __restrict__ Ht,
                                               const float* __restrict__ Wv,
                                               const float* __restrict__ bv,
                                               float* __restrict__ logits) {
    int tid = threadIdx.x;
    int u = blockIdx.x * 64 + (tid & 63);
    int b0 = __builtin_amdgcn_readfirstlane(tid >> 6) * 16;
    float acc[16] = {};
    const float* wcol = Wv + u;
    #pragma unroll 2
    for (int k = 0; k < NU; ++k) {
        float w = wcol[(size_t)k * NV];
        const float* ap = Ht + (size_t)k * NB + b0;          // wave-uniform base
        #pragma unroll
        for (int i = 0; i < 16; ++i) acc[i] = fmaf(ap[i], w, acc[i]);
    }
    float bvu = bv[u];
    #pragma unroll
    for (int i = 0; i < 16; ++i)
        logits[(size_t)(b0 + i) * NV + u] = acc[i] + bvu;
}

// ---- 7) row softmax over 32000 ---------------------------------------------
__global__ __launch_bounds__(256) void k_softmax(const float* __restrict__ logits,
                                                 float* __restrict__ y) {
    __shared__ float red[256];
    int b = blockIdx.x, tid = threadIdx.x;
    const float* row = logits + (size_t)b * NV;
    float m = -1e30f;
    for (int i = tid; i < NV; i += 256) m = fmaxf(m, row[i]);
    red[tid] = m; __syncthreads();
    for (int s = 128; s > 0; s >>= 1) {
        if (tid < s) red[tid] = fmaxf(red[tid], red[tid + s]);
        __syncthreads();
    }
    float M = red[0]; __syncthreads();
    float ssum = 0.0f;
    for (int i = tid; i < NV; i += 256) ssum += __expf(row[i] - M);
    red[tid] = ssum; __syncthreads();
    for (int s = 128; s > 0; s >>= 1) {
        if (tid < s) red[tid] += red[tid + s];
        __syncthreads();
    }
    float inv = 1.0f / red[0];
    for (int i = tid; i < NV; i += 256)
        y[(size_t)b * NV + i] = __expf(row[i] - M) * inv;
}

extern "C" void kernel_launch(void* const* d_in, const int* in_sizes, int n_in,
                              void* d_out, int out_size, void* d_ws, size_t ws_size,
                              hipStream_t stream) {
    const int*   X   = (const int*)d_in[0];
    const float* a   = (const float*)d_in[1];
    const float* h   = (const float*)d_in[2];
    const float* c   = (const float*)d_in[3];
    const float* emb = (const float*)d_in[4];
    // d_in[5..10] = W1,b1,W2,b2,We,be — dead (softmax over size-1 axis == 1)
    const float* Wx  = (const float*)d_in[11];
    const float* Wh  = (const float*)d_in[12];
    const float* bl  = (const float*)d_in[13];
    const float* Wv  = (const float*)d_in[14];
    const float* bv  = (const float*)d_in[15];

    float* out = (float*)d_out;
    float* ws  = (float*)d_ws;
    float* At      = ws + OFF_AT;
    float* zacc    = ws + OFF_Z;
    float* Ht      = ws + OFF_HT;
    float* scratch = ws + OFF_SCR;   // part[] then (after it's dead) logits[]

    float* out_y     = out + OUT_Y;
    float* out_ctx   = out + OUT_CTX;
    float* out_alpha = out + OUT_ALPHA;
    float* out_h     = out + OUT_H;
    float* out_c     = out + OUT_C;

    hipLaunchKernelGGL(k_zinit,   dim3(1024),     dim3(256), 0, stream, bl, zacc);
    hipLaunchKernelGGL(k_ctx,     dim3(NTC, NB),  dim3(256), 0, stream, a, scratch);
    hipLaunchKernelGGL(k_ctx_fin, dim3(NB),       dim3(128), 0, stream, scratch, X, emb, h, At, out_ctx, out_alpha);
    hipLaunchKernelGGL(k_zgemm,   dim3(G4/64, 8), dim3(256), 0, stream, At, Wx, Wh, zacc);
    hipLaunchKernelGGL(k_gates,   dim3(NB),       dim3(256), 0, stream, zacc, c, out_h, out_c, Ht);
    hipLaunchKernelGGL(k_vgemm,   dim3(NV/64),    dim3(256), 0, stream, Ht, Wv, bv, scratch);
    hipLaunchKernelGGL(k_softmax, dim3(NB),       dim3(256), 0, stream, scratch, out_y);
}